// Round 4
// baseline (829.519 us; speedup 1.0000x reference)
//
#include <hip/hip_runtime.h>
#include <hip/hip_fp16.h>

#define D     64
#define RPB   128           // rows per bucket (rowlocal = 7 bits)
#define BCAP  2560          // bucket capacity (mean 2048, sigma ~45 -> huge slack)
#define EPB   4096          // edges per bucket_kernel block
#define NBMAX 800           // max buckets (N=100000 -> 782)

// ---------------------------------------------------------------------------
// K_A: coarse bucket scatter. Per block: LDS histogram over buckets, one
//      global reservation atomic per (block,bucket), then scatter packed
//      (rowlocal<<17 | col) into bucket regions. cursor[b] ends = count(b).
// ---------------------------------------------------------------------------
__global__ __launch_bounds__(256) void bucket_kernel(const int* __restrict__ ei, int E,
                                                     int nb,
                                                     int* __restrict__ cursor,
                                                     int* __restrict__ bbuf) {
    __shared__ int hist[NBMAX];
    __shared__ int base_l[NBMAX];
    __shared__ int stage_v[EPB];
    __shared__ unsigned short stage_b[EPB];
    int tid = threadIdx.x;

    for (int i = tid; i < nb; i += 256) hist[i] = 0;
    __syncthreads();

    long long e0 = (long long)blockIdx.x * EPB;
#pragma unroll
    for (int i = 0; i < EPB / 256; ++i) {
        int idx = i * 256 + tid;
        long long e = e0 + idx;
        unsigned short b = 0xFFFF;
        int v = 0;
        if (e < E) {
            int r = ei[e];
            int c = ei[E + e];
            b = (unsigned short)(r >> 7);
            v = ((r & (RPB - 1)) << 17) | c;
            atomicAdd(&hist[b], 1);          // LDS atomic
        }
        stage_v[idx] = v;
        stage_b[idx] = b;
    }
    __syncthreads();

    for (int i = tid; i < nb; i += 256) {
        int c = hist[i];
        int base = (c > 0) ? atomicAdd(&cursor[i], c) : 0;  // one global atomic per (block,bucket)
        base_l[i] = base;
        hist[i] = 0;                         // reuse as local cursor
    }
    __syncthreads();

#pragma unroll
    for (int i = 0; i < EPB / 256; ++i) {
        int idx = i * 256 + tid;
        unsigned short b = stage_b[idx];
        if (b != 0xFFFF) {
            int off = base_l[b] + atomicAdd(&hist[b], 1);   // LDS atomic
            if (off < BCAP)                  // statistically impossible overflow guard
                bbuf[(size_t)b * BCAP + off] = stage_v[idx];
        }
    }
}

// ---------------------------------------------------------------------------
// K_B: per-bucket degree via LDS histogram -> dinv = rsqrt(deg) (coalesced).
//      Replaces the old deg kernel + 3 scan kernels.
// ---------------------------------------------------------------------------
__global__ __launch_bounds__(256) void deg_kernel(const int* __restrict__ cursor,
                                                  const int* __restrict__ bbuf,
                                                  float* __restrict__ dinv, int N) {
    __shared__ int deg[RPB];
    int b = blockIdx.x, tid = threadIdx.x;
    if (tid < RPB) deg[tid] = 0;
    __syncthreads();
    int cnt = min(cursor[b], BCAP);
    const int* buf = bbuf + (size_t)b * BCAP;
    for (int j = tid; j < cnt; j += 256) atomicAdd(&deg[buf[j] >> 17], 1);  // LDS atomic
    __syncthreads();
    int r = (b << 7) + tid;
    if (tid < RPB && r < N) {
        int d = deg[tid];
        dinv[r] = (d > 0) ? rsqrtf((float)d) : 0.0f;
    }
}

// ---------------------------------------------------------------------------
// K_C: xh[r][c] = dinv[r] * sum_k x[r][k] * W[c][k], stored fp16.
//      Lane c holds W row c in 64 VGPRs; broadcast via SALU readlane.
// ---------------------------------------------------------------------------
__global__ __launch_bounds__(256) void linear_kernel(const float* __restrict__ x,
                                                     const float* __restrict__ W,
                                                     const float* __restrict__ dinv,
                                                     __half* __restrict__ xh, int N) {
    int c  = threadIdx.x & 63;
    int wl = threadIdx.x >> 6;

    float w[D];
    const float4* W4 = (const float4*)(W + (size_t)c * D);
#pragma unroll
    for (int q = 0; q < D / 4; ++q) {
        float4 t = W4[q];
        w[4 * q + 0] = t.x; w[4 * q + 1] = t.y;
        w[4 * q + 2] = t.z; w[4 * q + 3] = t.w;
    }

    int stride = gridDim.x * 4;
    for (int r = blockIdx.x * 4 + wl; r < N; r += stride) {
        float xv = x[(size_t)r * D + c];
        float a0 = 0.f, a1 = 0.f, a2 = 0.f, a3 = 0.f;
#pragma unroll
        for (int k = 0; k < D; k += 4) {
            a0 = fmaf(__uint_as_float(__builtin_amdgcn_readlane(__float_as_uint(xv), k + 0)), w[k + 0], a0);
            a1 = fmaf(__uint_as_float(__builtin_amdgcn_readlane(__float_as_uint(xv), k + 1)), w[k + 1], a1);
            a2 = fmaf(__uint_as_float(__builtin_amdgcn_readlane(__float_as_uint(xv), k + 2)), w[k + 2], a2);
            a3 = fmaf(__uint_as_float(__builtin_amdgcn_readlane(__float_as_uint(xv), k + 3)), w[k + 3], a3);
        }
        float acc = (a0 + a1) + (a2 + a3);
        xh[(size_t)r * D + c] = __float2half(dinv[r] * acc);
    }
}

// ---------------------------------------------------------------------------
// K_D: per-bucket SpMM. 32 KB LDS fp32 acc tile (128 rows x 64 feats).
//      Wave grabs 64 packed edges (coalesced), broadcasts each via readlane,
//      gathers xh[col] (64 lanes x 2B = one 128 B txn), ds_add_f32 into the
//      row slot (bank = lane%32, 2-way aliasing = free). Sentinel col=N (zero
//      row in xh, rowlocal 0) makes tail chunks branch-free. One coalesced
//      float4 writeout per row scaled by dinv[r] -> no d_out memset, no
//      global atomics anywhere.
// ---------------------------------------------------------------------------
__global__ __launch_bounds__(256) void spmm_kernel(const int* __restrict__ cursor,
                                                   const int* __restrict__ bbuf,
                                                   const float* __restrict__ dinv,
                                                   const __half* __restrict__ xh,
                                                   float* __restrict__ out, int N) {
    __shared__ float acc[RPB * D];  // 32 KB
    int tid = threadIdx.x;
    float4* acc4 = (float4*)acc;
    for (int i = tid; i < RPB * (D / 4); i += 256) acc4[i] = make_float4(0.f, 0.f, 0.f, 0.f);
    __syncthreads();

    int b    = blockIdx.x;
    int cnt  = min(cursor[b], BCAP);
    const int* buf = bbuf + (size_t)b * BCAP;
    int lane = tid & 63;
    int wave = tid >> 6;

    for (int j0 = wave * 64; j0 < cnt; j0 += 256) {
        int j = j0 + lane;
        int v = (j < cnt) ? buf[j] : N;   // sentinel: rl=0, col=N (zero row)
#pragma unroll
        for (int k = 0; k < 64; k += 4) {
            int v0 = __builtin_amdgcn_readlane(v, k + 0);
            int v1 = __builtin_amdgcn_readlane(v, k + 1);
            int v2 = __builtin_amdgcn_readlane(v, k + 2);
            int v3 = __builtin_amdgcn_readlane(v, k + 3);
            float f0 = __half2float(xh[(size_t)(v0 & 0x1FFFF) * D + lane]);
            float f1 = __half2float(xh[(size_t)(v1 & 0x1FFFF) * D + lane]);
            float f2 = __half2float(xh[(size_t)(v2 & 0x1FFFF) * D + lane]);
            float f3 = __half2float(xh[(size_t)(v3 & 0x1FFFF) * D + lane]);
            atomicAdd(&acc[((v0 >> 17) << 6) + lane], f0);
            atomicAdd(&acc[((v1 >> 17) << 6) + lane], f1);
            atomicAdd(&acc[((v2 >> 17) << 6) + lane], f2);
            atomicAdd(&acc[((v3 >> 17) << 6) + lane], f3);
        }
    }
    __syncthreads();

    int r0 = b << 7;
    for (int i = tid; i < RPB * (D / 4); i += 256) {
        int row = i >> 4;                 // 16 float4 per row
        int r = r0 + row;
        if (r < N) {
            float4 a = acc4[i];
            float dr = dinv[r];
            ((float4*)out)[(size_t)r * (D / 4) + (i & 15)] =
                make_float4(dr * a.x, dr * a.y, dr * a.z, dr * a.w);
        }
    }
}

extern "C" void kernel_launch(void* const* d_in, const int* in_sizes, int n_in,
                              void* d_out, int out_size, void* d_ws, size_t ws_size,
                              hipStream_t stream) {
    const int*   ei = (const int*)d_in[0];   // (2,E) flat: [0..E) rows, [E..2E) cols
    const float* x  = (const float*)d_in[1]; // (N,64)
    const float* W  = (const float*)d_in[2]; // (64,64)
    float* out = (float*)d_out;              // (N,64)

    int E  = in_sizes[0] / 2;
    int N  = in_sizes[1] / D;
    int nb = (N + RPB - 1) / RPB;            // 782 for N=100000 (<= NBMAX)

    // Workspace layout (256 B aligned slices)
    char* p = (char*)d_ws;
    size_t off = 0;
    auto take = [&](size_t bytes) -> char* {
        char* cur = p + off;
        off = (off + bytes + 255) & ~(size_t)255;
        return cur;
    };
    float*  dinv   = (float*)take((size_t)N * 4);
    int*    cursor = (int*)take((size_t)nb * 4);
    int*    bbuf   = (int*)take((size_t)nb * BCAP * 4);
    __half* xh     = (__half*)take((size_t)(N + 1) * D * 2);  // +1 zero sentinel row
    (void)ws_size;

    hipMemsetAsync(cursor, 0, (size_t)nb * 4, stream);
    hipMemsetAsync(xh + (size_t)N * D, 0, D * sizeof(__half), stream);

    bucket_kernel<<<(E + EPB - 1) / EPB, 256, 0, stream>>>(ei, E, nb, cursor, bbuf);
    deg_kernel<<<nb, 256, 0, stream>>>(cursor, bbuf, dinv, N);
    linear_kernel<<<1024, 256, 0, stream>>>(x, W, dinv, xh, N);
    spmm_kernel<<<nb, 256, 0, stream>>>(cursor, bbuf, dinv, xh, out, N);
}

// Round 5
// 193.005 us; speedup vs baseline: 4.2979x; 4.2979x over previous
//
#include <hip/hip_runtime.h>
#include <hip/hip_fp16.h>

#define D     64
#define RPB   256            // rows per bucket (rowlocal = 8 bits, shift 17)
#define BCAP  4608           // capacity: mean 4096, sigma 64 -> +8 sigma slack
#define EPB   4096           // edges per bucket_kernel block
#define NBMAX 400            // max buckets (N=100000 -> 391)

// ---------------------------------------------------------------------------
// K1: coarse bucket scatter. Per block: LDS histogram over buckets, ONE
//     global reservation atomic per (block,bucket) (~150K total), scatter
//     packed (rowlocal<<17 | col) in ~10-int coalesced runs.
// ---------------------------------------------------------------------------
__global__ __launch_bounds__(256) void bucket_kernel(const int* __restrict__ ei, int E,
                                                     int nb,
                                                     int* __restrict__ cursor,
                                                     int* __restrict__ bbuf) {
    __shared__ int hist[NBMAX];
    __shared__ int base_l[NBMAX];
    __shared__ int stage_v[EPB];
    __shared__ unsigned short stage_b[EPB];
    int tid = threadIdx.x;

    for (int i = tid; i < nb; i += 256) hist[i] = 0;
    __syncthreads();

    long long e0 = (long long)blockIdx.x * EPB;
#pragma unroll
    for (int i = 0; i < EPB / 256; ++i) {
        int idx = i * 256 + tid;
        long long e = e0 + idx;
        unsigned short b = 0xFFFF;
        int v = 0;
        if (e < E) {
            int r = ei[e];
            int c = ei[E + e];
            b = (unsigned short)(r >> 8);
            v = ((r & (RPB - 1)) << 17) | c;
            atomicAdd(&hist[b], 1);                     // LDS atomic
        }
        stage_v[idx] = v;
        stage_b[idx] = b;
    }
    __syncthreads();

    for (int i = tid; i < nb; i += 256) {
        int c = hist[i];
        base_l[i] = (c > 0) ? atomicAdd(&cursor[i], c) : 0;  // 1 global atomic/(block,bucket)
        hist[i] = 0;                                     // reuse as local cursor
    }
    __syncthreads();

#pragma unroll
    for (int i = 0; i < EPB / 256; ++i) {
        int idx = i * 256 + tid;
        unsigned short b = stage_b[idx];
        if (b != 0xFFFF) {
            int off = base_l[b] + atomicAdd(&hist[b], 1);
            if (off < BCAP)                              // impossible-overflow guard
                bbuf[(size_t)b * BCAP + off] = stage_v[idx];
        }
    }
}

// ---------------------------------------------------------------------------
// K2: per-bucket counting sort (in place) + deg/dinv/rowinfo emission.
//     LDS: staged + sorted (2 x 18.4 KB) + hist/pfx/curs. All global reads
//     and the write-back are coalesced; all atomics are LDS.
//     rowinfo[r] = (global start in bbuf, deg).
// ---------------------------------------------------------------------------
__global__ __launch_bounds__(256) void sort_kernel(const int* __restrict__ cursor,
                                                   int* __restrict__ bbuf,
                                                   float* __restrict__ dinv,
                                                   int2* __restrict__ rowinfo, int N) {
    __shared__ int staged[BCAP];
    __shared__ int sorted[BCAP];
    __shared__ int hist[RPB];
    __shared__ int pfx[RPB];
    __shared__ int curs[RPB];
    int b = blockIdx.x, tid = threadIdx.x;
    int cnt = min(cursor[b], BCAP);
    int* gbuf = bbuf + (size_t)b * BCAP;

    hist[tid] = 0;
    __syncthreads();
    for (int j = tid; j < cnt; j += 256) {
        int v = gbuf[j];
        staged[j] = v;
        atomicAdd(&hist[v >> 17], 1);
    }
    __syncthreads();

    // exclusive prefix over 256 bins
    int dv = hist[tid];
    pfx[tid] = dv;
    __syncthreads();
    for (int off = 1; off < 256; off <<= 1) {
        int add = (tid >= off) ? pfx[tid - off] : 0;
        __syncthreads();
        pfx[tid] += add;
        __syncthreads();
    }
    int excl = pfx[tid] - dv;

    int r = (b << 8) + tid;
    if (r < N) {
        dinv[r] = (dv > 0) ? rsqrtf((float)dv) : 0.0f;
        rowinfo[r] = make_int2(b * BCAP + excl, dv);
    }
    curs[tid] = excl;
    __syncthreads();

    for (int j = tid; j < cnt; j += 256) {
        int val = staged[j];
        int pos = atomicAdd(&curs[val >> 17], 1);
        sorted[pos] = val;
    }
    __syncthreads();
    for (int j = tid; j < cnt; j += 256) gbuf[j] = sorted[j];
}

// ---------------------------------------------------------------------------
// K3: xh[r][c] = dinv[r] * sum_k x[r][k] * W[c][k], stored fp16.
//     Lane c holds W row c in 64 VGPRs; broadcast via SALU readlane.
// ---------------------------------------------------------------------------
__global__ __launch_bounds__(256) void linear_kernel(const float* __restrict__ x,
                                                     const float* __restrict__ W,
                                                     const float* __restrict__ dinv,
                                                     __half* __restrict__ xh, int N) {
    int c  = threadIdx.x & 63;
    int wl = threadIdx.x >> 6;

    float w[D];
    const float4* W4 = (const float4*)(W + (size_t)c * D);
#pragma unroll
    for (int q = 0; q < D / 4; ++q) {
        float4 t = W4[q];
        w[4 * q + 0] = t.x; w[4 * q + 1] = t.y;
        w[4 * q + 2] = t.z; w[4 * q + 3] = t.w;
    }

    int stride = gridDim.x * 4;
    for (int r = blockIdx.x * 4 + wl; r < N; r += stride) {
        float xv = x[(size_t)r * D + c];
        float a0 = 0.f, a1 = 0.f, a2 = 0.f, a3 = 0.f;
#pragma unroll
        for (int k = 0; k < D; k += 4) {
            a0 = fmaf(__uint_as_float(__builtin_amdgcn_readlane(__float_as_uint(xv), k + 0)), w[k + 0], a0);
            a1 = fmaf(__uint_as_float(__builtin_amdgcn_readlane(__float_as_uint(xv), k + 1)), w[k + 1], a1);
            a2 = fmaf(__uint_as_float(__builtin_amdgcn_readlane(__float_as_uint(xv), k + 2)), w[k + 2], a2);
            a3 = fmaf(__uint_as_float(__builtin_amdgcn_readlane(__float_as_uint(xv), k + 3)), w[k + 3], a3);
        }
        float acc = (a0 + a1) + (a2 + a3);
        xh[(size_t)r * D + c] = __float2half(dinv[r] * acc);
    }
}

// ---------------------------------------------------------------------------
// K4: gather SpMM, one wave per row (100K waves -> latency fully hidden).
//     cols read from sorted bbuf (coalesced, low17 = col); xh fp16 pre-scaled
//     by dinv[col] with zero sentinel row N (pad-to-8 branch-free). Half-wave
//     split: lanes 0-31 even edges, 32-63 odd; each lane loads half2 -> two
//     128 B txns per edge-pair, 4 in flight. Register accumulate, combine
//     via shfl, one coalesced 256 B store per row. No atomics, no memset.
// ---------------------------------------------------------------------------
__global__ __launch_bounds__(256) void spmm_kernel(const int2* __restrict__ rowinfo,
                                                   const int* __restrict__ bbuf,
                                                   const float* __restrict__ dinv,
                                                   const __half2* __restrict__ xh2,
                                                   float2* __restrict__ out2, int N) {
    int r = (blockIdx.x * 256 + threadIdx.x) >> 6;
    if (r >= N) return;
    int c   = threadIdx.x & 63;
    int sub = c >> 5;   // 0 = even edges, 1 = odd edges
    int f   = c & 31;   // feature-pair index

    int2 ri   = rowinfo[r];
    int start = ri.x;
    int d     = ri.y;
    float dr  = dinv[r];

    float ax = 0.f, ay = 0.f;
    for (int j0 = 0; j0 < d; j0 += 64) {     // single iteration for deg <= 64 (typ.)
        int n = d - j0;
        if (n > 64) n = 64;
        int cn_reg = (c < n) ? (bbuf[start + j0 + c] & 0x1FFFF) : N;
        int n8 = (n + 7) & ~7;
        for (int k = 0; k < n8; k += 8) {
            int e0 = __shfl(cn_reg, k + 0 + sub);
            int e1 = __shfl(cn_reg, k + 2 + sub);
            int e2 = __shfl(cn_reg, k + 4 + sub);
            int e3 = __shfl(cn_reg, k + 6 + sub);
            float2 v0 = __half22float2(xh2[(size_t)e0 * 32 + f]);
            float2 v1 = __half22float2(xh2[(size_t)e1 * 32 + f]);
            float2 v2 = __half22float2(xh2[(size_t)e2 * 32 + f]);
            float2 v3 = __half22float2(xh2[(size_t)e3 * 32 + f]);
            ax += (v0.x + v1.x) + (v2.x + v3.x);
            ay += (v0.y + v1.y) + (v2.y + v3.y);
        }
    }
    float sx = ax + __shfl(ax, c ^ 32);
    float sy = ay + __shfl(ay, c ^ 32);
    if (sub == 0) {
        out2[(size_t)r * 32 + f] = make_float2(dr * sx, dr * sy);
    }
}

extern "C" void kernel_launch(void* const* d_in, const int* in_sizes, int n_in,
                              void* d_out, int out_size, void* d_ws, size_t ws_size,
                              hipStream_t stream) {
    const int*   ei = (const int*)d_in[0];   // (2,E) flat: [0..E) rows, [E..2E) cols
    const float* x  = (const float*)d_in[1]; // (N,64)
    const float* W  = (const float*)d_in[2]; // (64,64)
    float* out = (float*)d_out;              // (N,64)

    int E  = in_sizes[0] / 2;
    int N  = in_sizes[1] / D;
    int nb = (N + RPB - 1) / RPB;            // 391 for N=100000 (<= NBMAX)

    // Workspace layout (256 B aligned slices) — ~21.2 MB total
    char* p = (char*)d_ws;
    size_t off = 0;
    auto take = [&](size_t bytes) -> char* {
        char* cur = p + off;
        off = (off + bytes + 255) & ~(size_t)255;
        return cur;
    };
    float*  dinv    = (float*)take((size_t)N * 4);
    int2*   rowinfo = (int2*)take((size_t)N * 8);
    int*    cursor  = (int*)take((size_t)nb * 4);
    int*    bbuf    = (int*)take((size_t)nb * BCAP * 4);
    __half* xh      = (__half*)take((size_t)(N + 1) * D * 2);  // +1 zero sentinel row
    (void)ws_size;

    hipMemsetAsync(cursor, 0, (size_t)nb * 4, stream);
    hipMemsetAsync(xh + (size_t)N * D, 0, D * sizeof(__half), stream);

    bucket_kernel<<<(E + EPB - 1) / EPB, 256, 0, stream>>>(ei, E, nb, cursor, bbuf);
    sort_kernel<<<nb, 256, 0, stream>>>(cursor, bbuf, dinv, rowinfo, N);
    linear_kernel<<<2048, 256, 0, stream>>>(x, W, dinv, xh, N);
    spmm_kernel<<<(N + 3) / 4, 256, 0, stream>>>(rowinfo, bbuf, dinv,
                                                 (const __half2*)xh, (float2*)out, N);
}

// Round 6
// 167.120 us; speedup vs baseline: 4.9636x; 1.1549x over previous
//
#include <hip/hip_runtime.h>
#include <hip/hip_fp16.h>

#define D     64
#define RPB   256            // rows per bucket (rowlocal = 8 bits, shift 17)
#define BCAP  4608           // capacity: mean 4096, sigma 64 -> +8 sigma slack
#define EPB   4096           // edges per bucket_kernel block
#define NBMAX 400            // max buckets (N=100000 -> 391)

typedef __attribute__((ext_vector_type(8))) _Float16 f16x8;
typedef __attribute__((ext_vector_type(4))) float    f32x4;

// ---------------------------------------------------------------------------
// K1: coarse bucket scatter. Per block: LDS histogram over buckets, ONE
//     global reservation atomic per (block,bucket) (~150K total), scatter
//     packed (rowlocal<<17 | col) in ~10-int coalesced runs.
// ---------------------------------------------------------------------------
__global__ __launch_bounds__(256) void bucket_kernel(const int* __restrict__ ei, int E,
                                                     int nb,
                                                     int* __restrict__ cursor,
                                                     int* __restrict__ bbuf) {
    __shared__ int hist[NBMAX];
    __shared__ int base_l[NBMAX];
    __shared__ int stage_v[EPB];
    __shared__ unsigned short stage_b[EPB];
    int tid = threadIdx.x;

    for (int i = tid; i < nb; i += 256) hist[i] = 0;
    __syncthreads();

    long long e0 = (long long)blockIdx.x * EPB;
#pragma unroll
    for (int i = 0; i < EPB / 256; ++i) {
        int idx = i * 256 + tid;
        long long e = e0 + idx;
        unsigned short b = 0xFFFF;
        int v = 0;
        if (e < E) {
            int r = ei[e];
            int c = ei[E + e];
            b = (unsigned short)(r >> 8);
            v = ((r & (RPB - 1)) << 17) | c;
            atomicAdd(&hist[b], 1);                     // LDS atomic
        }
        stage_v[idx] = v;
        stage_b[idx] = b;
    }
    __syncthreads();

    for (int i = tid; i < nb; i += 256) {
        int c = hist[i];
        base_l[i] = (c > 0) ? atomicAdd(&cursor[i], c) : 0;  // 1 global atomic/(block,bucket)
        hist[i] = 0;                                     // reuse as local cursor
    }
    __syncthreads();

#pragma unroll
    for (int i = 0; i < EPB / 256; ++i) {
        int idx = i * 256 + tid;
        unsigned short b = stage_b[idx];
        if (b != 0xFFFF) {
            int off = base_l[b] + atomicAdd(&hist[b], 1);
            if (off < BCAP)                              // impossible-overflow guard
                bbuf[(size_t)b * BCAP + off] = stage_v[idx];
        }
    }
}

// ---------------------------------------------------------------------------
// K2: per-bucket counting sort (in place) + deg/dinv/rowinfo emission.
//     Slimmed: no staged[] copy — bucket is read twice from global (L2-hot,
//     16 KB/block). LDS 21 KB -> ~7 blocks/CU (was 40 KB -> 4).
// ---------------------------------------------------------------------------
__global__ __launch_bounds__(256) void sort_kernel(const int* __restrict__ cursor,
                                                   int* __restrict__ bbuf,
                                                   float* __restrict__ dinv,
                                                   int2* __restrict__ rowinfo, int N) {
    __shared__ int sorted[BCAP];
    __shared__ int hist[RPB];
    __shared__ int pfx[RPB];
    __shared__ int curs[RPB];
    int b = blockIdx.x, tid = threadIdx.x;
    int cnt = min(cursor[b], BCAP);
    int* gbuf = bbuf + (size_t)b * BCAP;

    hist[tid] = 0;
    __syncthreads();
    for (int j = tid; j < cnt; j += 256) atomicAdd(&hist[gbuf[j] >> 17], 1);
    __syncthreads();

    // exclusive prefix over 256 bins
    int dv = hist[tid];
    pfx[tid] = dv;
    __syncthreads();
    for (int off = 1; off < 256; off <<= 1) {
        int add = (tid >= off) ? pfx[tid - off] : 0;
        __syncthreads();
        pfx[tid] += add;
        __syncthreads();
    }
    int excl = pfx[tid] - dv;

    int r = (b << 8) + tid;
    if (r < N) {
        dinv[r] = (dv > 0) ? rsqrtf((float)dv) : 0.0f;
        rowinfo[r] = make_int2(b * BCAP + excl, dv);
    }
    curs[tid] = excl;
    __syncthreads();

    for (int j = tid; j < cnt; j += 256) {
        int v = gbuf[j];                 // second read, L2-hot
        int pos = atomicAdd(&curs[v >> 17], 1);
        sorted[pos] = v;
    }
    __syncthreads();
    for (int j = tid; j < cnt; j += 256) gbuf[j] = sorted[j];
}

// ---------------------------------------------------------------------------
// K3: xh[r][c] = dinv[r] * sum_k x[r][k] * W[c][k], fp16 out, via MFMA.
//     mfma_f32_16x16x32_f16; one wave per 16-row tile. B (= W^T) lives in
//     8 f16x8 fragments per lane, loaded once. Per tile: 4x float4 A loads,
//     2 MFMAs per col-group (K=64 = 2x32), 16 coalesced 32 B half stores.
//     Layouts (verified m89/m120): A[m=lane&15][k=quad*8+j],
//     B[k=quad*8+j][n=lane&15], D row=quad*4+reg col=lane&15.
//     Block 0 also zeroes the sentinel row xh[N][*].
// ---------------------------------------------------------------------------
__global__ __launch_bounds__(256) void linear_kernel(const float* __restrict__ x,
                                                     const float* __restrict__ W,
                                                     const float* __restrict__ dinv,
                                                     __half* __restrict__ xh, int M) {
    int tid  = threadIdx.x;
    int lane = tid & 63;
    int wv   = tid >> 6;
    int r16  = lane & 15;   // A row within tile / D col
    int quad = lane >> 4;   // 0..3

    if (blockIdx.x == 0 && tid < D) xh[(size_t)M * D + tid] = __float2half(0.0f);

    // B fragments: Bf[g][s] = W[16g + r16][32s + quad*8 + j], j=0..7
    f16x8 Bf[4][2];
#pragma unroll
    for (int g = 0; g < 4; ++g)
#pragma unroll
        for (int s = 0; s < 2; ++s) {
            const float4* wp = (const float4*)(W + (size_t)(16 * g + r16) * D + 32 * s + quad * 8);
            float4 w0 = wp[0], w1 = wp[1];
            f16x8 h;
            h[0] = (_Float16)w0.x; h[1] = (_Float16)w0.y;
            h[2] = (_Float16)w0.z; h[3] = (_Float16)w0.w;
            h[4] = (_Float16)w1.x; h[5] = (_Float16)w1.y;
            h[6] = (_Float16)w1.z; h[7] = (_Float16)w1.w;
            Bf[g][s] = h;
        }

    int ntiles = (M + 15) / 16;
    int stride = gridDim.x * 4;
    for (int t = blockIdx.x * 4 + wv; t < ntiles; t += stride) {
        int r0 = t * 16;
        int ra = min(r0 + r16, M - 1);
        const float4* xp = (const float4*)(x + (size_t)ra * D + quad * 8);
        // A fragments for kstep 0 (k = quad*8..+8) and kstep 1 (+32 floats = +8 float4)
        float4 a0 = xp[0], a1 = xp[1], a2 = xp[8], a3 = xp[9];
        f16x8 A0, A1;
        A0[0] = (_Float16)a0.x; A0[1] = (_Float16)a0.y; A0[2] = (_Float16)a0.z; A0[3] = (_Float16)a0.w;
        A0[4] = (_Float16)a1.x; A0[5] = (_Float16)a1.y; A0[6] = (_Float16)a1.z; A0[7] = (_Float16)a1.w;
        A1[0] = (_Float16)a2.x; A1[1] = (_Float16)a2.y; A1[2] = (_Float16)a2.z; A1[3] = (_Float16)a2.w;
        A1[4] = (_Float16)a3.x; A1[5] = (_Float16)a3.y; A1[6] = (_Float16)a3.z; A1[7] = (_Float16)a3.w;

        f32x4 acc[4];
#pragma unroll
        for (int g = 0; g < 4; ++g) {
            f32x4 z = {0.f, 0.f, 0.f, 0.f};
            z = __builtin_amdgcn_mfma_f32_16x16x32_f16(A0, Bf[g][0], z, 0, 0, 0);
            acc[g] = __builtin_amdgcn_mfma_f32_16x16x32_f16(A1, Bf[g][1], z, 0, 0, 0);
        }

#pragma unroll
        for (int reg = 0; reg < 4; ++reg) {
            int rr = r0 + quad * 4 + reg;
            if (rr < M) {
                float dvr = dinv[rr];
                __half* op = xh + (size_t)rr * D + r16;
#pragma unroll
                for (int g = 0; g < 4; ++g)
                    op[16 * g] = __float2half(dvr * acc[g][reg]);
            }
        }
    }
}

// ---------------------------------------------------------------------------
// K4: gather SpMM, one wave per row (100K waves -> latency hidden).
//     cols from sorted bbuf (coalesced); xh fp16 pre-scaled by dinv[col],
//     zero sentinel row N. Half-wave split, 4 gathers (128 B each) in
//     flight, register accumulate, one coalesced 256 B store per row.
// ---------------------------------------------------------------------------
__global__ __launch_bounds__(256) void spmm_kernel(const int2* __restrict__ rowinfo,
                                                   const int* __restrict__ bbuf,
                                                   const float* __restrict__ dinv,
                                                   const __half2* __restrict__ xh2,
                                                   float2* __restrict__ out2, int N) {
    int r = (blockIdx.x * 256 + threadIdx.x) >> 6;
    if (r >= N) return;
    int c   = threadIdx.x & 63;
    int sub = c >> 5;   // 0 = even edges, 1 = odd edges
    int f   = c & 31;   // feature-pair index

    int2 ri   = rowinfo[r];
    int start = ri.x;
    int d     = ri.y;
    float dr  = dinv[r];

    float ax = 0.f, ay = 0.f;
    for (int j0 = 0; j0 < d; j0 += 64) {
        int n = d - j0;
        if (n > 64) n = 64;
        int cn_reg = (c < n) ? (bbuf[start + j0 + c] & 0x1FFFF) : N;
        int n8 = (n + 7) & ~7;
        for (int k = 0; k < n8; k += 8) {
            int e0 = __shfl(cn_reg, k + 0 + sub);
            int e1 = __shfl(cn_reg, k + 2 + sub);
            int e2 = __shfl(cn_reg, k + 4 + sub);
            int e3 = __shfl(cn_reg, k + 6 + sub);
            float2 v0 = __half22float2(xh2[(size_t)e0 * 32 + f]);
            float2 v1 = __half22float2(xh2[(size_t)e1 * 32 + f]);
            float2 v2 = __half22float2(xh2[(size_t)e2 * 32 + f]);
            float2 v3 = __half22float2(xh2[(size_t)e3 * 32 + f]);
            ax += (v0.x + v1.x) + (v2.x + v3.x);
            ay += (v0.y + v1.y) + (v2.y + v3.y);
        }
    }
    float sx = ax + __shfl(ax, c ^ 32);
    float sy = ay + __shfl(ay, c ^ 32);
    if (sub == 0) {
        out2[(size_t)r * 32 + f] = make_float2(dr * sx, dr * sy);
    }
}

extern "C" void kernel_launch(void* const* d_in, const int* in_sizes, int n_in,
                              void* d_out, int out_size, void* d_ws, size_t ws_size,
                              hipStream_t stream) {
    const int*   ei = (const int*)d_in[0];   // (2,E) flat: [0..E) rows, [E..2E) cols
    const float* x  = (const float*)d_in[1]; // (N,64)
    const float* W  = (const float*)d_in[2]; // (64,64)
    float* out = (float*)d_out;              // (N,64)

    int E  = in_sizes[0] / 2;
    int N  = in_sizes[1] / D;
    int nb = (N + RPB - 1) / RPB;            // 391 for N=100000 (<= NBMAX)

    // Workspace layout (256 B aligned slices) — ~21.2 MB total
    char* p = (char*)d_ws;
    size_t off = 0;
    auto take = [&](size_t bytes) -> char* {
        char* cur = p + off;
        off = (off + bytes + 255) & ~(size_t)255;
        return cur;
    };
    float*  dinv    = (float*)take((size_t)N * 4);
    int2*   rowinfo = (int2*)take((size_t)N * 8);
    int*    cursor  = (int*)take((size_t)nb * 4);
    int*    bbuf    = (int*)take((size_t)nb * BCAP * 4);
    __half* xh      = (__half*)take((size_t)(N + 1) * D * 2);  // +1 zero sentinel row
    (void)ws_size;

    hipMemsetAsync(cursor, 0, (size_t)nb * 4, stream);

    bucket_kernel<<<(E + EPB - 1) / EPB, 256, 0, stream>>>(ei, E, nb, cursor, bbuf);
    sort_kernel<<<nb, 256, 0, stream>>>(cursor, bbuf, dinv, rowinfo, N);
    linear_kernel<<<1024, 256, 0, stream>>>(x, W, dinv, xh, N);
    spmm_kernel<<<(N + 3) / 4, 256, 0, stream>>>(rowinfo, bbuf, dinv,
                                                 (const __half2*)xh, (float2*)out, N);
}

// Round 7
// 166.020 us; speedup vs baseline: 4.9965x; 1.0066x over previous
//
#include <hip/hip_runtime.h>
#include <hip/hip_fp16.h>

#define D     64
#define RPB   256            // rows per bucket (rowlocal = 8 bits, shift 17)
#define BCAP  4608           // capacity: mean 4096, sigma 64 -> +8 sigma slack
#define EPB   2048           // edges per bucket_kernel block (782 blocks -> 12 waves/CU)
#define NBMAX 400            // max buckets (N=100000 -> 391)

typedef __attribute__((ext_vector_type(8))) _Float16 f16x8;
typedef __attribute__((ext_vector_type(4))) float    f32x4;

// ---------------------------------------------------------------------------
// K1: coarse bucket scatter. Per block: LDS histogram over buckets, ONE
//     global reservation atomic per (block,bucket), scatter packed
//     (rowlocal<<17 | col). EPB=2048 -> 782 blocks = 12 waves/CU (TLP).
// ---------------------------------------------------------------------------
__global__ __launch_bounds__(256) void bucket_kernel(const int* __restrict__ ei, int E,
                                                     int nb,
                                                     int* __restrict__ cursor,
                                                     int* __restrict__ bbuf) {
    __shared__ int hist[NBMAX];
    __shared__ int base_l[NBMAX];
    __shared__ int stage_v[EPB];
    __shared__ unsigned short stage_b[EPB];
    int tid = threadIdx.x;

    for (int i = tid; i < nb; i += 256) hist[i] = 0;
    __syncthreads();

    long long e0 = (long long)blockIdx.x * EPB;
#pragma unroll
    for (int i = 0; i < EPB / 256; ++i) {
        int idx = i * 256 + tid;
        long long e = e0 + idx;
        unsigned short b = 0xFFFF;
        int v = 0;
        if (e < E) {
            int r = ei[e];
            int c = ei[E + e];
            b = (unsigned short)(r >> 8);
            v = ((r & (RPB - 1)) << 17) | c;
            atomicAdd(&hist[b], 1);                     // LDS atomic
        }
        stage_v[idx] = v;
        stage_b[idx] = b;
    }
    __syncthreads();

    for (int i = tid; i < nb; i += 256) {
        int c = hist[i];
        base_l[i] = (c > 0) ? atomicAdd(&cursor[i], c) : 0;  // 1 global atomic/(block,bucket)
        hist[i] = 0;                                     // reuse as local cursor
    }
    __syncthreads();

#pragma unroll
    for (int i = 0; i < EPB / 256; ++i) {
        int idx = i * 256 + tid;
        unsigned short b = stage_b[idx];
        if (b != 0xFFFF) {
            int off = base_l[b] + atomicAdd(&hist[b], 1);
            if (off < BCAP)                              // impossible-overflow guard
                bbuf[(size_t)b * BCAP + off] = stage_v[idx];
        }
    }
}

// ---------------------------------------------------------------------------
// K2: per-bucket counting sort (in place) + deg/dinv/rowinfo emission.
//     512 threads/block (391 blocks -> 12 waves/CU). Bucket read twice from
//     global (L2-hot) instead of LDS staging; all atomics LDS.
// ---------------------------------------------------------------------------
__global__ __launch_bounds__(512) void sort_kernel(const int* __restrict__ cursor,
                                                   int* __restrict__ bbuf,
                                                   float* __restrict__ dinv,
                                                   int2* __restrict__ rowinfo, int N) {
    __shared__ int sorted[BCAP];
    __shared__ int hist[RPB];
    __shared__ int pfx[RPB];
    __shared__ int curs[RPB];
    int b = blockIdx.x, tid = threadIdx.x;
    int cnt = min(cursor[b], BCAP);
    int* gbuf = bbuf + (size_t)b * BCAP;

    if (tid < RPB) hist[tid] = 0;
    __syncthreads();
    for (int j = tid; j < cnt; j += 512) atomicAdd(&hist[gbuf[j] >> 17], 1);
    __syncthreads();

    // exclusive prefix over 256 bins (tid<256 active; all threads hit syncs)
    int dv = 0;
    if (tid < RPB) { dv = hist[tid]; pfx[tid] = dv; }
    __syncthreads();
    for (int off = 1; off < RPB; off <<= 1) {
        int add = 0;
        if (tid < RPB && tid >= off) add = pfx[tid - off];
        __syncthreads();
        if (tid < RPB) pfx[tid] += add;
        __syncthreads();
    }

    if (tid < RPB) {
        int excl = pfx[tid] - dv;
        int r = (b << 8) + tid;
        if (r < N) {
            dinv[r] = (dv > 0) ? rsqrtf((float)dv) : 0.0f;
            rowinfo[r] = make_int2(b * BCAP + excl, dv);
        }
        curs[tid] = excl;
    }
    __syncthreads();

    for (int j = tid; j < cnt; j += 512) {
        int v = gbuf[j];                 // second read, L2-hot
        int pos = atomicAdd(&curs[v >> 17], 1);
        sorted[pos] = v;
    }
    __syncthreads();
    for (int j = tid; j < cnt; j += 512) gbuf[j] = sorted[j];
}

// ---------------------------------------------------------------------------
// K3: xh[r][c] = dinv[r] * sum_k x[r][k] * W[c][k], fp16 out, via MFMA
//     (mfma_f32_16x16x32_f16, one wave per 16-row tile, W resident in VGPRs).
//     Block 0 also zeroes the sentinel row xh[N][*].
// ---------------------------------------------------------------------------
__global__ __launch_bounds__(256) void linear_kernel(const float* __restrict__ x,
                                                     const float* __restrict__ W,
                                                     const float* __restrict__ dinv,
                                                     __half* __restrict__ xh, int M) {
    int tid  = threadIdx.x;
    int lane = tid & 63;
    int wv   = tid >> 6;
    int r16  = lane & 15;   // A row within tile / D col
    int quad = lane >> 4;   // 0..3

    if (blockIdx.x == 0 && tid < D) xh[(size_t)M * D + tid] = __float2half(0.0f);

    // B fragments: Bf[g][s] = W[16g + r16][32s + quad*8 + j], j=0..7
    f16x8 Bf[4][2];
#pragma unroll
    for (int g = 0; g < 4; ++g)
#pragma unroll
        for (int s = 0; s < 2; ++s) {
            const float4* wp = (const float4*)(W + (size_t)(16 * g + r16) * D + 32 * s + quad * 8);
            float4 w0 = wp[0], w1 = wp[1];
            f16x8 h;
            h[0] = (_Float16)w0.x; h[1] = (_Float16)w0.y;
            h[2] = (_Float16)w0.z; h[3] = (_Float16)w0.w;
            h[4] = (_Float16)w1.x; h[5] = (_Float16)w1.y;
            h[6] = (_Float16)w1.z; h[7] = (_Float16)w1.w;
            Bf[g][s] = h;
        }

    int ntiles = (M + 15) / 16;
    int stride = gridDim.x * 4;
    for (int t = blockIdx.x * 4 + wv; t < ntiles; t += stride) {
        int r0 = t * 16;
        int ra = min(r0 + r16, M - 1);
        const float4* xp = (const float4*)(x + (size_t)ra * D + quad * 8);
        float4 a0 = xp[0], a1 = xp[1], a2 = xp[8], a3 = xp[9];
        f16x8 A0, A1;
        A0[0] = (_Float16)a0.x; A0[1] = (_Float16)a0.y; A0[2] = (_Float16)a0.z; A0[3] = (_Float16)a0.w;
        A0[4] = (_Float16)a1.x; A0[5] = (_Float16)a1.y; A0[6] = (_Float16)a1.z; A0[7] = (_Float16)a1.w;
        A1[0] = (_Float16)a2.x; A1[1] = (_Float16)a2.y; A1[2] = (_Float16)a2.z; A1[3] = (_Float16)a2.w;
        A1[4] = (_Float16)a3.x; A1[5] = (_Float16)a3.y; A1[6] = (_Float16)a3.z; A1[7] = (_Float16)a3.w;

        f32x4 acc[4];
#pragma unroll
        for (int g = 0; g < 4; ++g) {
            f32x4 z = {0.f, 0.f, 0.f, 0.f};
            z = __builtin_amdgcn_mfma_f32_16x16x32_f16(A0, Bf[g][0], z, 0, 0, 0);
            acc[g] = __builtin_amdgcn_mfma_f32_16x16x32_f16(A1, Bf[g][1], z, 0, 0, 0);
        }

#pragma unroll
        for (int reg = 0; reg < 4; ++reg) {
            int rr = r0 + quad * 4 + reg;
            if (rr < M) {
                float dvr = dinv[rr];
                __half* op = xh + (size_t)rr * D + r16;
#pragma unroll
                for (int g = 0; g < 4; ++g)
                    op[16 * g] = __float2half(dvr * acc[g][reg]);
            }
        }
    }
}

// ---------------------------------------------------------------------------
// K4: gather SpMM, one wave per row (100K waves). 16 edges per inner iter ->
//     8 independent 128 B gathers in flight (2x MLP vs R6). Nontemporal
//     output stores keep xh resident in L2. No atomics, no memset.
// ---------------------------------------------------------------------------
__global__ __launch_bounds__(256) void spmm_kernel(const int2* __restrict__ rowinfo,
                                                   const int* __restrict__ bbuf,
                                                   const float* __restrict__ dinv,
                                                   const __half2* __restrict__ xh2,
                                                   float2* __restrict__ out2, int N) {
    int r = (blockIdx.x * 256 + threadIdx.x) >> 6;
    if (r >= N) return;
    int c   = threadIdx.x & 63;
    int sub = c >> 5;   // 0 = even edges, 1 = odd edges
    int f   = c & 31;   // feature-pair index

    int2 ri   = rowinfo[r];
    int start = ri.x;
    int d     = ri.y;
    float dr  = dinv[r];

    float ax = 0.f, ay = 0.f;
    for (int j0 = 0; j0 < d; j0 += 64) {
        int n = d - j0;
        if (n > 64) n = 64;
        int cn_reg = (c < n) ? (bbuf[start + j0 + c] & 0x1FFFF) : N;
        int n16 = (n + 15) & ~15;
        for (int k = 0; k < n16; k += 16) {
            int e0 = __shfl(cn_reg, k +  0 + sub);
            int e1 = __shfl(cn_reg, k +  2 + sub);
            int e2 = __shfl(cn_reg, k +  4 + sub);
            int e3 = __shfl(cn_reg, k +  6 + sub);
            int e4 = __shfl(cn_reg, k +  8 + sub);
            int e5 = __shfl(cn_reg, k + 10 + sub);
            int e6 = __shfl(cn_reg, k + 12 + sub);
            int e7 = __shfl(cn_reg, k + 14 + sub);
            float2 v0 = __half22float2(xh2[(size_t)e0 * 32 + f]);
            float2 v1 = __half22float2(xh2[(size_t)e1 * 32 + f]);
            float2 v2 = __half22float2(xh2[(size_t)e2 * 32 + f]);
            float2 v3 = __half22float2(xh2[(size_t)e3 * 32 + f]);
            float2 v4 = __half22float2(xh2[(size_t)e4 * 32 + f]);
            float2 v5 = __half22float2(xh2[(size_t)e5 * 32 + f]);
            float2 v6 = __half22float2(xh2[(size_t)e6 * 32 + f]);
            float2 v7 = __half22float2(xh2[(size_t)e7 * 32 + f]);
            ax += ((v0.x + v1.x) + (v2.x + v3.x)) + ((v4.x + v5.x) + (v6.x + v7.x));
            ay += ((v0.y + v1.y) + (v2.y + v3.y)) + ((v4.y + v5.y) + (v6.y + v7.y));
        }
    }
    float sx = ax + __shfl(ax, c ^ 32);
    float sy = ay + __shfl(ay, c ^ 32);
    if (sub == 0) {
        float2 res = make_float2(dr * sx, dr * sy);
        __builtin_nontemporal_store(__builtin_bit_cast(double, res),
                                    (double*)&out2[(size_t)r * 32 + f]);
    }
}

extern "C" void kernel_launch(void* const* d_in, const int* in_sizes, int n_in,
                              void* d_out, int out_size, void* d_ws, size_t ws_size,
                              hipStream_t stream) {
    const int*   ei = (const int*)d_in[0];   // (2,E) flat: [0..E) rows, [E..2E) cols
    const float* x  = (const float*)d_in[1]; // (N,64)
    const float* W  = (const float*)d_in[2]; // (64,64)
    float* out = (float*)d_out;              // (N,64)

    int E  = in_sizes[0] / 2;
    int N  = in_sizes[1] / D;
    int nb = (N + RPB - 1) / RPB;            // 391 for N=100000 (<= NBMAX)

    // Workspace layout (256 B aligned slices) — ~21.2 MB total
    char* p = (char*)d_ws;
    size_t off = 0;
    auto take = [&](size_t bytes) -> char* {
        char* cur = p + off;
        off = (off + bytes + 255) & ~(size_t)255;
        return cur;
    };
    float*  dinv    = (float*)take((size_t)N * 4);
    int2*   rowinfo = (int2*)take((size_t)N * 8);
    int*    cursor  = (int*)take((size_t)nb * 4);
    int*    bbuf    = (int*)take((size_t)nb * BCAP * 4);
    __half* xh      = (__half*)take((size_t)(N + 1) * D * 2);  // +1 zero sentinel row
    (void)ws_size;

    hipMemsetAsync(cursor, 0, (size_t)nb * 4, stream);

    bucket_kernel<<<(E + EPB - 1) / EPB, 256, 0, stream>>>(ei, E, nb, cursor, bbuf);
    sort_kernel<<<nb, 512, 0, stream>>>(cursor, bbuf, dinv, rowinfo, N);
    linear_kernel<<<1024, 256, 0, stream>>>(x, W, dinv, xh, N);
    spmm_kernel<<<(N + 3) / 4, 256, 0, stream>>>(rowinfo, bbuf, dinv,
                                                 (const __half2*)xh, (float2*)out, N);
}

// Round 8
// 164.655 us; speedup vs baseline: 5.0379x; 1.0083x over previous
//
#include <hip/hip_runtime.h>
#include <hip/hip_fp16.h>

#define D     64
#define RPB   256            // rows per bucket (rowlocal = 8 bits, shift 17)
#define BCAP  4608           // capacity: mean 4096, sigma 64 -> +8 sigma slack
#define EPB   4096           // edges per bucket_kernel block (391 blocks x 8 waves)
#define NBMAX 400            // max buckets (N=100000 -> 391)

typedef __attribute__((ext_vector_type(8))) _Float16 f16x8;
typedef __attribute__((ext_vector_type(4))) float    f32x4;

// ---------------------------------------------------------------------------
// K1: coarse bucket scatter, no LDS staging (edges re-read from L2 in the
//     scatter pass). LDS = 3.2 KB -> occupancy-unconstrained. 391 blocks x
//     512 thr = 12 waves/CU. One reservation atomic per (block,bucket)
//     (~153K total), runs ~10 ints -> ~42 B coalesced per scatter run.
// ---------------------------------------------------------------------------
__global__ __launch_bounds__(512) void bucket_kernel(const int* __restrict__ ei, int E,
                                                     int nb,
                                                     int* __restrict__ cursor,
                                                     int* __restrict__ bbuf) {
    __shared__ int hist[NBMAX];
    __shared__ int base_l[NBMAX];
    int tid = threadIdx.x;

    for (int i = tid; i < nb; i += 512) hist[i] = 0;
    __syncthreads();

    int e0 = blockIdx.x * EPB;
    int n  = min(EPB, E - e0);

    for (int idx = tid; idx < n; idx += 512)
        atomicAdd(&hist[ei[e0 + idx] >> 8], 1);          // LDS atomic
    __syncthreads();

    for (int i = tid; i < nb; i += 512) {
        int c = hist[i];
        base_l[i] = (c > 0) ? atomicAdd(&cursor[i], c) : 0;  // 1 global atomic/(block,bucket)
        hist[i] = 0;                                     // reuse as local cursor
    }
    __syncthreads();

    for (int idx = tid; idx < n; idx += 512) {
        int r = ei[e0 + idx];                            // L2-hot re-read
        int c = ei[E + e0 + idx];
        int b = r >> 8;
        int off = base_l[b] + atomicAdd(&hist[b], 1);
        if (off < BCAP)                                  // impossible-overflow guard
            bbuf[(size_t)b * BCAP + off] = ((r & (RPB - 1)) << 17) | c;
    }
}

// ---------------------------------------------------------------------------
// K2: per-bucket counting sort (in place) + dinv + rowinfo(int4).
//     512 thr, 391 blocks. Shfl-based bin scan (2 barriers, not 16).
//     rowinfo[r] = (start, deg, bits(dinv[r]), 0).
// ---------------------------------------------------------------------------
__global__ __launch_bounds__(512) void sort_kernel(const int* __restrict__ cursor,
                                                   int* __restrict__ bbuf,
                                                   float* __restrict__ dinv,
                                                   int4* __restrict__ rowinfo, int N) {
    __shared__ int sorted[BCAP];
    __shared__ int hist[RPB];
    __shared__ int curs[RPB];
    __shared__ int wsum[4];
    int b = blockIdx.x, tid = threadIdx.x;
    int cnt = min(cursor[b], BCAP);
    int* gbuf = bbuf + (size_t)b * BCAP;

    if (tid < RPB) hist[tid] = 0;
    __syncthreads();
    for (int j = tid; j < cnt; j += 512) atomicAdd(&hist[gbuf[j] >> 17], 1);
    __syncthreads();

    // exclusive prefix over 256 bins: waves 0-3 scan 64 bins each via shfl
    int dv = 0, s = 0;
    if (tid < RPB) {
        dv = hist[tid];
        s = dv;
#pragma unroll
        for (int off = 1; off < 64; off <<= 1) {
            int t = __shfl_up(s, off);
            if ((tid & 63) >= off) s += t;
        }
        if ((tid & 63) == 63) wsum[tid >> 6] = s;
    }
    __syncthreads();
    if (tid < RPB) {
        int woff = 0;
#pragma unroll
        for (int i = 0; i < 3; ++i)
            if ((tid >> 6) > i) woff += wsum[i];
        int excl = s + woff - dv;                        // exclusive prefix
        int r = (b << 8) + tid;
        if (r < N) {
            float di = (dv > 0) ? rsqrtf((float)dv) : 0.0f;
            dinv[r] = di;
            rowinfo[r] = make_int4(b * BCAP + excl, dv, __float_as_int(di), 0);
        }
        curs[tid] = excl;
    }
    __syncthreads();

    for (int j = tid; j < cnt; j += 512) {
        int v = gbuf[j];                                 // second read, L2-hot
        int pos = atomicAdd(&curs[v >> 17], 1);
        sorted[pos] = v;
    }
    __syncthreads();
    for (int j = tid; j < cnt; j += 512) gbuf[j] = sorted[j];
}

// ---------------------------------------------------------------------------
// K3: xh[r][c] = dinv[r] * sum_k x[r][k] * W[c][k], fp16 out, via MFMA
//     (mfma_f32_16x16x32_f16, one wave per 16-row tile, W resident in VGPRs).
//     Block 0 also zeroes the sentinel row xh[N][*].
// ---------------------------------------------------------------------------
__global__ __launch_bounds__(256) void linear_kernel(const float* __restrict__ x,
                                                     const float* __restrict__ W,
                                                     const float* __restrict__ dinv,
                                                     __half* __restrict__ xh, int M) {
    int tid  = threadIdx.x;
    int lane = tid & 63;
    int wv   = tid >> 6;
    int r16  = lane & 15;   // A row within tile / D col
    int quad = lane >> 4;   // 0..3

    if (blockIdx.x == 0 && tid < D) xh[(size_t)M * D + tid] = __float2half(0.0f);

    // B fragments: Bf[g][s] = W[16g + r16][32s + quad*8 + j], j=0..7
    f16x8 Bf[4][2];
#pragma unroll
    for (int g = 0; g < 4; ++g)
#pragma unroll
        for (int s = 0; s < 2; ++s) {
            const float4* wp = (const float4*)(W + (size_t)(16 * g + r16) * D + 32 * s + quad * 8);
            float4 w0 = wp[0], w1 = wp[1];
            f16x8 h;
            h[0] = (_Float16)w0.x; h[1] = (_Float16)w0.y;
            h[2] = (_Float16)w0.z; h[3] = (_Float16)w0.w;
            h[4] = (_Float16)w1.x; h[5] = (_Float16)w1.y;
            h[6] = (_Float16)w1.z; h[7] = (_Float16)w1.w;
            Bf[g][s] = h;
        }

    int ntiles = (M + 15) / 16;
    int stride = gridDim.x * 4;
    for (int t = blockIdx.x * 4 + wv; t < ntiles; t += stride) {
        int r0 = t * 16;
        int ra = min(r0 + r16, M - 1);
        const float4* xp = (const float4*)(x + (size_t)ra * D + quad * 8);
        float4 a0 = xp[0], a1 = xp[1], a2 = xp[8], a3 = xp[9];
        f16x8 A0, A1;
        A0[0] = (_Float16)a0.x; A0[1] = (_Float16)a0.y; A0[2] = (_Float16)a0.z; A0[3] = (_Float16)a0.w;
        A0[4] = (_Float16)a1.x; A0[5] = (_Float16)a1.y; A0[6] = (_Float16)a1.z; A0[7] = (_Float16)a1.w;
        A1[0] = (_Float16)a2.x; A1[1] = (_Float16)a2.y; A1[2] = (_Float16)a2.z; A1[3] = (_Float16)a2.w;
        A1[4] = (_Float16)a3.x; A1[5] = (_Float16)a3.y; A1[6] = (_Float16)a3.z; A1[7] = (_Float16)a3.w;

        f32x4 acc[4];
#pragma unroll
        for (int g = 0; g < 4; ++g) {
            f32x4 z = {0.f, 0.f, 0.f, 0.f};
            z = __builtin_amdgcn_mfma_f32_16x16x32_f16(A0, Bf[g][0], z, 0, 0, 0);
            acc[g] = __builtin_amdgcn_mfma_f32_16x16x32_f16(A1, Bf[g][1], z, 0, 0, 0);
        }

#pragma unroll
        for (int reg = 0; reg < 4; ++reg) {
            int rr = r0 + quad * 4 + reg;
            if (rr < M) {
                float dvr = dinv[rr];
                __half* op = xh + (size_t)rr * D + r16;
#pragma unroll
                for (int g = 0; g < 4; ++g)
                    op[16 * g] = __float2half(dvr * acc[g][reg]);
            }
        }
    }
}

// ---------------------------------------------------------------------------
// K4: gather SpMM, software-pipelined grid-stride rows (~8 rows/wave).
//     rowinfo (start, deg, dinv-bits) prefetched 2 rows ahead; col vector
//     1 row ahead -> the rowinfo->cols->gathers dependence chain overlaps a
//     full row of gather work. 16 edges/iter = 8 x 128 B gathers in flight.
//     Nontemporal output stores. No atomics, no memset.
// ---------------------------------------------------------------------------
__global__ __launch_bounds__(256) void spmm_kernel(const int4* __restrict__ rowinfo,
                                                   const int* __restrict__ bbuf,
                                                   const __half2* __restrict__ xh2,
                                                   float2* __restrict__ out2,
                                                   int N, int stride) {
    int wid = (blockIdx.x * 256 + threadIdx.x) >> 6;
    int c   = threadIdx.x & 63;
    int sub = c >> 5;   // 0 = even edges, 1 = odd edges
    int f   = c & 31;   // feature-pair index

    int r0 = wid;
    if (r0 >= N) return;

    int4 ri0 = rowinfo[r0];
    int4 ri1 = (r0 + stride < N) ? rowinfo[r0 + stride] : make_int4(0, 0, 0, 0);
    int  cn0 = (c < min(ri0.y, 64)) ? (bbuf[ri0.x + c] & 0x1FFFF) : N;

    for (int r = r0; r < N; r += stride) {
        int rn  = r + stride;
        int rn2 = rn + stride;
        // prefetch rowinfo two ahead, cols one ahead (ri1 already resident)
        int4 ri2 = (rn2 < N) ? rowinfo[rn2] : make_int4(0, 0, 0, 0);
        int  cn1 = (rn < N && c < min(ri1.y, 64)) ? (bbuf[ri1.x + c] & 0x1FFFF) : N;

        int   d  = ri0.y;
        float dr = __int_as_float(ri0.z);
        float ax = 0.f, ay = 0.f;

        int n = min(d, 64);
        int n16 = (n + 15) & ~15;
        for (int k = 0; k < n16; k += 16) {
            int e0 = __shfl(cn0, k +  0 + sub);
            int e1 = __shfl(cn0, k +  2 + sub);
            int e2 = __shfl(cn0, k +  4 + sub);
            int e3 = __shfl(cn0, k +  6 + sub);
            int e4 = __shfl(cn0, k +  8 + sub);
            int e5 = __shfl(cn0, k + 10 + sub);
            int e6 = __shfl(cn0, k + 12 + sub);
            int e7 = __shfl(cn0, k + 14 + sub);
            float2 v0 = __half22float2(xh2[(size_t)e0 * 32 + f]);
            float2 v1 = __half22float2(xh2[(size_t)e1 * 32 + f]);
            float2 v2 = __half22float2(xh2[(size_t)e2 * 32 + f]);
            float2 v3 = __half22float2(xh2[(size_t)e3 * 32 + f]);
            float2 v4 = __half22float2(xh2[(size_t)e4 * 32 + f]);
            float2 v5 = __half22float2(xh2[(size_t)e5 * 32 + f]);
            float2 v6 = __half22float2(xh2[(size_t)e6 * 32 + f]);
            float2 v7 = __half22float2(xh2[(size_t)e7 * 32 + f]);
            ax += ((v0.x + v1.x) + (v2.x + v3.x)) + ((v4.x + v5.x) + (v6.x + v7.x));
            ay += ((v0.y + v1.y) + (v2.y + v3.y)) + ((v4.y + v5.y) + (v6.y + v7.y));
        }
        for (int j0 = 64; j0 < d; j0 += 64) {            // rare (deg > 64)
            int nn = min(d - j0, 64);
            int cnx = (c < nn) ? (bbuf[ri0.x + j0 + c] & 0x1FFFF) : N;
            int m16 = (nn + 15) & ~15;
            for (int k = 0; k < m16; k += 16) {
                int e0 = __shfl(cnx, k +  0 + sub);
                int e1 = __shfl(cnx, k +  2 + sub);
                int e2 = __shfl(cnx, k +  4 + sub);
                int e3 = __shfl(cnx, k +  6 + sub);
                int e4 = __shfl(cnx, k +  8 + sub);
                int e5 = __shfl(cnx, k + 10 + sub);
                int e6 = __shfl(cnx, k + 12 + sub);
                int e7 = __shfl(cnx, k + 14 + sub);
                float2 v0 = __half22float2(xh2[(size_t)e0 * 32 + f]);
                float2 v1 = __half22float2(xh2[(size_t)e1 * 32 + f]);
                float2 v2 = __half22float2(xh2[(size_t)e2 * 32 + f]);
                float2 v3 = __half22float2(xh2[(size_t)e3 * 32 + f]);
                float2 v4 = __half22float2(xh2[(size_t)e4 * 32 + f]);
                float2 v5 = __half22float2(xh2[(size_t)e5 * 32 + f]);
                float2 v6 = __half22float2(xh2[(size_t)e6 * 32 + f]);
                float2 v7 = __half22float2(xh2[(size_t)e7 * 32 + f]);
                ax += ((v0.x + v1.x) + (v2.x + v3.x)) + ((v4.x + v5.x) + (v6.x + v7.x));
                ay += ((v0.y + v1.y) + (v2.y + v3.y)) + ((v4.y + v5.y) + (v6.y + v7.y));
            }
        }

        float sx = ax + __shfl(ax, c ^ 32);
        float sy = ay + __shfl(ay, c ^ 32);
        if (sub == 0) {
            float2 res = make_float2(dr * sx, dr * sy);
            __builtin_nontemporal_store(__builtin_bit_cast(double, res),
                                        (double*)&out2[(size_t)r * 32 + f]);
        }
        ri0 = ri1; ri1 = ri2; cn0 = cn1;
    }
}

extern "C" void kernel_launch(void* const* d_in, const int* in_sizes, int n_in,
                              void* d_out, int out_size, void* d_ws, size_t ws_size,
                              hipStream_t stream) {
    const int*   ei = (const int*)d_in[0];   // (2,E) flat: [0..E) rows, [E..2E) cols
    const float* x  = (const float*)d_in[1]; // (N,64)
    const float* W  = (const float*)d_in[2]; // (64,64)
    float* out = (float*)d_out;              // (N,64)

    int E  = in_sizes[0] / 2;
    int N  = in_sizes[1] / D;
    int nb = (N + RPB - 1) / RPB;            // 391 for N=100000 (<= NBMAX)

    // Workspace layout (256 B aligned slices) — ~22 MB total
    char* p = (char*)d_ws;
    size_t off = 0;
    auto take = [&](size_t bytes) -> char* {
        char* cur = p + off;
        off = (off + bytes + 255) & ~(size_t)255;
        return cur;
    };
    float*  dinv    = (float*)take((size_t)N * 4);
    int4*   rowinfo = (int4*)take((size_t)N * 16);
    int*    cursor  = (int*)take((size_t)nb * 4);
    int*    bbuf    = (int*)take((size_t)nb * BCAP * 4);
    __half* xh      = (__half*)take((size_t)(N + 1) * D * 2);  // +1 zero sentinel row
    (void)ws_size;

    hipMemsetAsync(cursor, 0, (size_t)nb * 4, stream);

    bucket_kernel<<<(E + EPB - 1) / EPB, 512, 0, stream>>>(ei, E, nb, cursor, bbuf);
    sort_kernel<<<nb, 512, 0, stream>>>(cursor, bbuf, dinv, rowinfo, N);
    linear_kernel<<<1024, 256, 0, stream>>>(x, W, dinv, xh, N);

    int spmm_blocks = 3072;                  // 12288 waves, ~8 rows/wave
    spmm_kernel<<<spmm_blocks, 256, 0, stream>>>(rowinfo, bbuf, (const __half2*)xh,
                                                 (float2*)out, N, spmm_blocks * 4);
}